// Round 11
// baseline (287.341 us; speedup 1.0000x reference)
//
#include <hip/hip_runtime.h>

// Fused block, all-bf16 dataflow. GEMMs: 8-phase 512-thread template
// (BM=256/128, BN=256, BK=64, st_16x32 LDS swizzle, counted vmcnt, setprio);
// DECAY on a 4-wave BK=32 m97-style kernel (16 KiB LDS, 6 blocks/CU -> all
// 544 tril tiles co-resident, no scheduling tail); YO on the 4-wave 64 KiB
// variant with complementary-K pairing (2 blocks/CU). Algebraic folds:
// S = (D@W_qk)@D^T (W_qk = wq wk^T), wo folded into v: v' = D@(wv wo).

typedef __bf16 bf16x8 __attribute__((ext_vector_type(8)));
typedef unsigned short u16x8 __attribute__((ext_vector_type(8)));
typedef float f32x4 __attribute__((ext_vector_type(4)));

constexpr int Bb = 4, Ll = 2048, Dd = 1024, DIc = 2048;
constexpr long LD  = (long)Ll * Dd;   // 2,097,152
constexpr long BLD = (long)Bb * LD;   // 8,388,608

static __device__ __forceinline__ unsigned short f2bf(float f) {
  unsigned u = __builtin_bit_cast(unsigned, f);
  u += 0x7fffu + ((u >> 16) & 1u);  // RNE
  return (unsigned short)(u >> 16);
}
static __device__ __forceinline__ float bf2f(unsigned short u) {
  return __builtin_bit_cast(float, (unsigned)u << 16);
}
static __device__ __forceinline__ float silu(float g) {
  return g / (1.f + __expf(-g));
}

enum { EP_UG = 0, EP_DOWN, EP_GV, EP_YO };

#define STAGE_A(DBUF, MG, KH, TILE) {                                          \
    const int kt_ = ((TILE) < NTm1 ? (TILE) : NTm1);                           \
    __builtin_amdgcn_global_load_lds(                                          \
      (const __attribute__((address_space(1))) void*)                          \
        (Ag + (size_t)(aRow + (MG)*64) * lda + kt_*64 + (KH)*32 + aCol),       \
      (__attribute__((address_space(3))) void*)                                \
        (lds + (DBUF)*ADB + (KH)*AKH + (aRb + (MG)*4)*512), 16, 0, 0); }

#define STAGE_B(DBUF, NH, KH, TILE) {                                          \
    const int kt_ = ((TILE) < NTm1 ? (TILE) : NTm1);                           \
    __builtin_amdgcn_global_load_lds(                                          \
      (const __attribute__((address_space(1))) void*)                          \
        (Bg + (size_t)(bRow + (NH)*128) * ldb + kt_*64 + (KH)*32 + aCol),      \
      (__attribute__((address_space(3))) void*)                                \
        (lds + BOFF + (DBUF)*16384 + (KH)*8192 + ((NH)*8 + w)*512), 16, 0, 0); }

#define LOAD_A(DBUF, KS, MG) {                                                 \
  _Pragma("unroll") for (int j_ = 0; j_ < 4; ++j_)                             \
    af[j_] = *(const bf16x8*)&lds[(DBUF)*ADB + (KS)*AKH +                      \
        (aRdBase + (MG)*4 + j_)*512 + fr*32 + cph]; }

#define LOAD_B(DBUF, KS) {                                                     \
  _Pragma("unroll") for (int n_ = 0; n_ < 4; ++n_)                             \
    bfr[KS][n_] = *(const bf16x8*)&lds[BOFF + (DBUF)*16384 + (KS)*8192 +       \
        (bRb + n_)*512 + fr*32 + cph]; }

#define MFMA_PH(KS, MG) {                                                      \
  __builtin_amdgcn_s_setprio(1);                                               \
  _Pragma("unroll") for (int j_ = 0; j_ < 4; ++j_)                             \
  _Pragma("unroll") for (int n_ = 0; n_ < 4; ++n_)                             \
    acc[(MG)*4 + j_][n_] = __builtin_amdgcn_mfma_f32_16x16x32_bf16(            \
        af[j_], bfr[KS][n_], acc[(MG)*4 + j_][n_], 0, 0, 0);                   \
  __builtin_amdgcn_s_setprio(0); }

#define BAR() __builtin_amdgcn_s_barrier()
#define WAIT_LGKM0() { asm volatile("s_waitcnt lgkmcnt(0)" ::: "memory");      \
                       __builtin_amdgcn_sched_barrier(0); }
#define WAIT_LGKM8() asm volatile("s_waitcnt lgkmcnt(8)" ::: "memory")
#define WAIT_VM(N) asm volatile("s_waitcnt vmcnt(" #N ")" ::: "memory")

template <int EPI, int BM>
__global__ __launch_bounds__(512, 2) void gemm8_k(
    const ushort* __restrict__ A, const ushort* __restrict__ Bm,
    void* __restrict__ O0, const float* __restrict__ bias,
    const float* __restrict__ bias2,
    int K, int lda, int ldb, int ldc,
    long sA, long sB, long sC,
    void* __restrict__ O1) {
  constexpr int MF = BM / 32;
  constexpr int ADB = BM * 64;
  constexpr int AKH = BM * 32;
  constexpr int BOFF = BM * 128;
  __shared__ ushort lds[BM == 256 ? 65536 : 49152];

  const int z = blockIdx.z;
  const int gx = gridDim.x;
  const int nwg = gx * gridDim.y;
  const int id = blockIdx.y * gx + blockIdx.x;
  const int chunk = nwg >> 3;
  const int swz = (id & 7) * chunk + (id >> 3);
  const int m0 = (swz / gx) * BM;
  const int n0 = (swz % gx) * 256;

  const int t = threadIdx.x;
  const int lane = t & 63;
  const int w = t >> 6;

  const ushort* Ag = A + (size_t)z * sA + (size_t)m0 * lda;
  const ushort* Bg = Bm + (size_t)z * sB + (size_t)n0 * ldb;

  const int NT = K >> 6;
  const int NTm1 = NT - 1;
  const int NI = NT >> 1;

  // stage-side: lane' pre-applies the st_16x32 swizzle
  const int lp = lane ^ (((lane >> 5) & 1) << 1);
  const int aCol = (lp & 3) * 8;
  const int bRow = (w >> 2) * 64 + (w & 3) * 16 + (lp >> 2);
  int aRow, aRb, aRdBase;
  if constexpr (BM == 256) {
    aRow = (w >> 2) * 128 + (w & 3) * 16 + (lp >> 2);
    aRb = (w >> 2) * 8 + (w & 3);
    aRdBase = (w >> 2) * 8;
  } else {
    aRow = w * 16 + (lp >> 2);
    aRb = w;
    aRdBase = (w >> 2) * 4;
  }
  // read-side
  const int fr = lane & 15;
  const int kg = (lane >> 4) * 8;
  const int cph = kg ^ (((fr >> 3) & 1) << 4);
  const int bRb = ((w & 3) >> 1) * 8 + ((w & 3) & 1) * 4;

  f32x4 acc[MF][4] = {};
  bf16x8 af[4], bfr[2][4];

  if constexpr (BM == 256) {
    STAGE_A(0, 0, 0, 0); STAGE_A(0, 0, 1, 0); STAGE_A(0, 1, 0, 0); STAGE_A(0, 1, 1, 0);
    STAGE_B(0, 0, 0, 0); STAGE_B(0, 0, 1, 0); STAGE_B(0, 1, 0, 0); STAGE_B(0, 1, 1, 0);
    STAGE_B(1, 0, 0, 1); STAGE_B(1, 0, 1, 1); STAGE_B(1, 1, 0, 1); STAGE_B(1, 1, 1, 1);
    STAGE_A(1, 0, 0, 1); STAGE_A(1, 0, 1, 1);
    WAIT_VM(6);
    BAR();
    for (int i = 0; i < NI; ++i) {
      const int tt = 2 * i;
      LOAD_B(0, 0); LOAD_B(0, 1); LOAD_A(0, 0, 0);
      STAGE_A(1, 1, 0, tt + 1); STAGE_A(1, 1, 1, tt + 1);
      WAIT_LGKM8();
      BAR(); WAIT_LGKM0();
      MFMA_PH(0, 0);
      BAR();
      LOAD_A(0, 0, 1);
      STAGE_B(0, 0, 0, tt + 2); STAGE_B(0, 1, 0, tt + 2);
      BAR(); WAIT_LGKM0();
      MFMA_PH(0, 1);
      BAR();
      LOAD_A(0, 1, 0);
      STAGE_B(0, 0, 1, tt + 2); STAGE_B(0, 1, 1, tt + 2);
      BAR(); WAIT_LGKM0();
      MFMA_PH(1, 0);
      BAR();
      LOAD_A(0, 1, 1);
      STAGE_A(0, 0, 0, tt + 2); STAGE_A(0, 0, 1, tt + 2);
      WAIT_VM(6);
      BAR(); WAIT_LGKM0();
      MFMA_PH(1, 1);
      BAR();
      LOAD_B(1, 0); LOAD_B(1, 1); LOAD_A(1, 0, 0);
      STAGE_A(0, 1, 0, tt + 2); STAGE_A(0, 1, 1, tt + 2);
      WAIT_LGKM8();
      BAR(); WAIT_LGKM0();
      MFMA_PH(0, 0);
      BAR();
      LOAD_A(1, 0, 1);
      STAGE_B(1, 0, 0, tt + 3); STAGE_B(1, 1, 0, tt + 3);
      BAR(); WAIT_LGKM0();
      MFMA_PH(0, 1);
      BAR();
      LOAD_A(1, 1, 0);
      STAGE_B(1, 0, 1, tt + 3); STAGE_B(1, 1, 1, tt + 3);
      BAR(); WAIT_LGKM0();
      MFMA_PH(1, 0);
      BAR();
      LOAD_A(1, 1, 1);
      STAGE_A(1, 0, 0, tt + 3); STAGE_A(1, 0, 1, tt + 3);
      WAIT_VM(6);
      BAR(); WAIT_LGKM0();
      MFMA_PH(1, 1);
      BAR();
    }
  } else {
    STAGE_A(0, 0, 0, 0); STAGE_A(0, 0, 1, 0);
    STAGE_B(0, 0, 0, 0); STAGE_B(0, 1, 0, 0); STAGE_B(0, 0, 1, 0); STAGE_B(0, 1, 1, 0);
    STAGE_B(1, 0, 0, 1); STAGE_B(1, 1, 0, 1); STAGE_B(1, 0, 1, 1); STAGE_B(1, 1, 1, 1);
    WAIT_VM(4);
    BAR();
    for (int i = 0; i < NI; ++i) {
      const int tt = 2 * i;
      LOAD_B(0, 0); LOAD_B(0, 1); LOAD_A(0, 0, 0);
      STAGE_A(1, 0, 0, tt + 1); STAGE_A(1, 0, 1, tt + 1);
      WAIT_LGKM8();
      BAR(); WAIT_LGKM0();
      MFMA_PH(0, 0);
      BAR();
      LOAD_A(0, 1, 0);
      STAGE_B(0, 0, 0, tt + 2); STAGE_B(0, 1, 0, tt + 2);
      STAGE_B(0, 0, 1, tt + 2); STAGE_B(0, 1, 1, tt + 2);
      WAIT_VM(4);
      BAR(); WAIT_LGKM0();
      MFMA_PH(1, 0);
      BAR();
      LOAD_B(1, 0); LOAD_B(1, 1); LOAD_A(1, 0, 0);
      STAGE_A(0, 0, 0, tt + 2); STAGE_A(0, 0, 1, tt + 2);
      WAIT_LGKM8();
      BAR(); WAIT_LGKM0();
      MFMA_PH(0, 0);
      BAR();
      LOAD_A(1, 1, 0);
      STAGE_B(1, 0, 0, tt + 3); STAGE_B(1, 1, 0, tt + 3);
      STAGE_B(1, 0, 1, tt + 3); STAGE_B(1, 1, 1, tt + 3);
      WAIT_VM(4);
      BAR(); WAIT_LGKM0();
      MFMA_PH(1, 0);
      BAR();
    }
  }

  // ---- epilogue ---- C/D: col=lane&15, row=(lane>>4)*4+reg
  const int rb4 = (lane >> 4) * 4;
  const int wm = (w >> 2) * (BM / 2), wn = (w & 3) * 64;

#pragma unroll
  for (int mf = 0; mf < MF; ++mf) {
#pragma unroll
    for (int nf = 0; nf < 4; ++nf) {
      const int gm0 = m0 + wm + mf * 16 + rb4;
      const int gn = n0 + wn + nf * 16 + fr;
      if constexpr (EPI == EP_GV) {
        if (gn < 1024) {  // G half: plain bf16
#pragma unroll
          for (int r = 0; r < 4; ++r)
            ((ushort*)O0)[(size_t)(gm0 + r) * 1024 + gn] = f2bf(acc[mf][nf][r]);
        } else {  // v' half: transposed write vT[b][d][t]
          const int d = gn - 1024, b = gm0 >> 11, ttp = gm0 & 2047;
          ushort4 w4;
          w4.x = f2bf(acc[mf][nf][0]); w4.y = f2bf(acc[mf][nf][1]);
          w4.z = f2bf(acc[mf][nf][2]); w4.w = f2bf(acc[mf][nf][3]);
          *(ushort4*)&((ushort*)O1)[(size_t)b * LD + (size_t)d * Ll + ttp] = w4;
        }
      } else {
#pragma unroll
        for (int r = 0; r < 4; ++r) {
          const int gm = gm0 + r;
          const size_t idx = (size_t)z * sC + (size_t)gm * ldc + gn;
          const float v = acc[mf][nf][r];
          if constexpr (EPI == EP_UG) {
            const float b = (gn < 2048) ? bias[gn] : bias2[gn - 2048];
            ((ushort*)O0)[idx] = f2bf(v + b);
          } else {  // EP_DOWN
            ((ushort*)O0)[idx] = f2bf(v + bias[gn]);
          }
        }
      }
    }
  }
}

// ---- DECAY: 4-wave BK=32 m97-style 128x128 kernel, 16 KiB LDS, ~6 blocks/CU
// so all 544 tril tiles are co-resident (no 2-blocks/CU scheduling tail).
// S = tril(G @ D^T) * d^(t-s).
__global__ __launch_bounds__(256) void decay_k(
    const ushort* __restrict__ A, const ushort* __restrict__ Bm,
    ushort* __restrict__ S, const float* __restrict__ decayp) {
  __shared__ ushort lds[8192];
  ushort* As = lds;
  ushort* Bs = lds + 4096;

  const int z = blockIdx.z;
  const int gx = gridDim.x;
  const int nwg = gx * gridDim.y;
  const int id = blockIdx.y * gx + blockIdx.x;
  const int chunk = nwg >> 3;
  const int swz = (id & 7) * chunk + (id >> 3);
  const int m0 = (swz / gx) * 128;
  const int n0 = (swz % gx) * 128;
  if (n0 > m0) return;  // above diagonal: never read by YO (K-clamp)

  const ushort* Ab = A + (size_t)z * LD + (size_t)m0 * 1024;
  const ushort* Bb = Bm + (size_t)z * LD + (size_t)n0 * 1024;

  const int t = threadIdx.x;
  const int lane = t & 63;
  const int wave = t >> 6;
  const int wm = (wave >> 1) * 64, wn = (wave & 1) * 64;
  const int fr = lane & 15, kg = (lane >> 4) * 8;
  const int srow0 = wave * 16 + (lane >> 2), scol = (lane & 3) * 8;

  f32x4 acc[4][4] = {};

  for (int k0 = 0; k0 < 1024; k0 += 32) {
#pragma unroll
    for (int p = 0; p < 2; ++p) {
      __builtin_amdgcn_global_load_lds(
          (const __attribute__((address_space(1))) void*)
              (Ab + (size_t)(srow0 + p * 64) * 1024 + k0 + scol),
          (__attribute__((address_space(3))) void*)(As + (p * 4 + wave) * 512),
          16, 0, 0);
      __builtin_amdgcn_global_load_lds(
          (const __attribute__((address_space(1))) void*)
              (Bb + (size_t)(srow0 + p * 64) * 1024 + k0 + scol),
          (__attribute__((address_space(3))) void*)(Bs + (p * 4 + wave) * 512),
          16, 0, 0);
    }
    __syncthreads();
    bf16x8 af[4], bv[4];
#pragma unroll
    for (int i = 0; i < 4; ++i) {
      af[i] = *(const bf16x8*)&As[(wm + i * 16 + fr) * 32 + kg];
      bv[i] = *(const bf16x8*)&Bs[(wn + i * 16 + fr) * 32 + kg];
    }
#pragma unroll
    for (int mi = 0; mi < 4; ++mi)
#pragma unroll
      for (int ni = 0; ni < 4; ++ni)
        acc[mi][ni] = __builtin_amdgcn_mfma_f32_16x16x32_bf16(
            af[mi], bv[ni], acc[mi][ni], 0, 0, 0);
    __syncthreads();
  }

  const int rb = (lane >> 4) * 4;
  const float logd = __logf(decayp[0]);
  ushort* Sz = S + (size_t)z * Ll * Ll;
#pragma unroll
  for (int mi = 0; mi < 4; ++mi) {
#pragma unroll
    for (int ni = 0; ni < 4; ++ni) {
      const int gn = n0 + wn + ni * 16 + fr;
#pragma unroll
      for (int r = 0; r < 4; ++r) {
        const int gm = m0 + wm + mi * 16 + rb + r;
        Sz[(size_t)gm * Ll + gn] =
            (gn <= gm) ? f2bf(acc[mi][ni][r] * __expf((float)(gm - gn) * logd))
                       : (ushort)0;
      }
    }
  }
}

// ---- YO: 4-wave (256-thread) BM=128/BN=128, 64 KiB LDS, 2 blocks/CU,
// complementary-K pairing. out = x + S @ v'.
#define S4A(DBUF, MG, KH, TILE) {                                              \
    const int kt_ = ((TILE) < NTm1 ? (TILE) : NTm1);                           \
    __builtin_amdgcn_global_load_lds(                                          \
      (const __attribute__((address_space(1))) void*)                          \
        (Ag + (size_t)(sRow + (MG)*64) * lda + kt_*64 + (KH)*32 + sCol),       \
      (__attribute__((address_space(3))) void*)                                \
        (lds + (DBUF)*8192 + (KH)*4096 + ((MG)*4 + w4)*512), 16, 0, 0); }

#define S4B(DBUF, NH, KH, TILE) {                                              \
    const int kt_ = ((TILE) < NTm1 ? (TILE) : NTm1);                           \
    __builtin_amdgcn_global_load_lds(                                          \
      (const __attribute__((address_space(1))) void*)                          \
        (Bg + (size_t)(sRow + (NH)*64) * ldb + kt_*64 + (KH)*32 + sCol),       \
      (__attribute__((address_space(3))) void*)                                \
        (lds + 16384 + (DBUF)*8192 + (KH)*4096 + ((NH)*4 + w4)*512), 16, 0, 0); }

#define L4A(DBUF, KS) {                                                        \
  _Pragma("unroll") for (int j_ = 0; j_ < 4; ++j_)                             \
    af[j_] = *(const bf16x8*)&lds[(DBUF)*8192 + (KS)*4096 +                    \
        (aRd + j_)*512 + fr*32 + cph]; }

#define L4B(DBUF, KS) {                                                        \
  _Pragma("unroll") for (int n_ = 0; n_ < 4; ++n_)                             \
    bfr[KS][n_] = *(const bf16x8*)&lds[16384 + (DBUF)*8192 + (KS)*4096 +       \
        (bRd + n_)*512 + fr*32 + cph]; }

#define MFMA4(KS) {                                                            \
  __builtin_amdgcn_s_setprio(1);                                               \
  _Pragma("unroll") for (int j_ = 0; j_ < 4; ++j_)                             \
  _Pragma("unroll") for (int n_ = 0; n_ < 4; ++n_)                             \
    acc[j_][n_] = __builtin_amdgcn_mfma_f32_16x16x32_bf16(                     \
        af[j_], bfr[KS][n_], acc[j_][n_], 0, 0, 0);                            \
  __builtin_amdgcn_s_setprio(0); }

__global__ __launch_bounds__(256, 2) void yo_k(
    const ushort* __restrict__ A, const ushort* __restrict__ Bm,
    float* __restrict__ O0, const float* __restrict__ xres,
    int lda, int ldb, int ldc, long sA, long sB, long sC) {
  __shared__ ushort lds[32768];  // 64 KiB

  const int t = threadIdx.x;
  const int lane = t & 63;
  const int w4 = t >> 6;

  // grid (8,64) flat; id and id+256 -> complementary m-tiles (i, 15-i)
  const int id = blockIdx.y * gridDim.x + blockIdx.x;
  const int half = id >> 8;
  const int u = id & 255;
  const int nt = u & 7;
  const int rem = u >> 3;  // 0..31
  const int z = rem >> 3;
  const int i8 = rem & 7;
  const int mt = half ? (15 - i8) : i8;
  const int m0 = mt * 128;
  const int n0 = nt * 128;

  const ushort* Ag = A + (size_t)z * sA + (size_t)m0 * lda;
  const ushort* Bg = Bm + (size_t)z * sB + (size_t)n0 * ldb;

  const int Kend = m0 + 128;  // causal K-clamp
  const int NT = Kend >> 6;
  const int NTm1 = NT - 1;
  const int NI = NT >> 1;

  const int lp = lane ^ (((lane >> 5) & 1) << 1);
  const int sRow = w4 * 16 + (lp >> 2);
  const int sCol = (lp & 3) * 8;
  const int fr = lane & 15;
  const int kg = (lane >> 4) * 8;
  const int cph = kg ^ (((fr >> 3) & 1) << 4);
  const int aRd = (w4 >> 1) * 4;  // wm = (w4>>1)*64
  const int bRd = (w4 & 1) * 4;   // wn = (w4&1)*64

  f32x4 acc[4][4] = {};
  bf16x8 af[4], bfr[2][4];

  // prologue: A0(4) + B0(4) + B1(4); vmcnt(4) leaves B1 in flight
  S4A(0, 0, 0, 0); S4A(0, 1, 0, 0); S4A(0, 0, 1, 0); S4A(0, 1, 1, 0);
  S4B(0, 0, 0, 0); S4B(0, 1, 0, 0); S4B(0, 0, 1, 0); S4B(0, 1, 1, 0);
  S4B(1, 0, 0, 1); S4B(1, 1, 0, 1); S4B(1, 0, 1, 1); S4B(1, 1, 1, 1);
  WAIT_VM(4);
  BAR();
  for (int i = 0; i < NI; ++i) {
    const int tt = 2 * i;
    L4B(0, 0); L4B(0, 1); L4A(0, 0);
    S4A(1, 0, 0, tt + 1); S4A(1, 1, 0, tt + 1);
    S4A(1, 0, 1, tt + 1); S4A(1, 1, 1, tt + 1);
    WAIT_LGKM8();
    BAR(); WAIT_LGKM0();
    MFMA4(0);
    BAR();
    L4A(0, 1);
    S4B(0, 0, 0, tt + 2); S4B(0, 1, 0, tt + 2);
    S4B(0, 0, 1, tt + 2); S4B(0, 1, 1, tt + 2);
    WAIT_VM(4);
    BAR(); WAIT_LGKM0();
    MFMA4(1);
    BAR();
    L4B(1, 0); L4B(1, 1); L4A(1, 0);
    S4A(0, 0, 0, tt + 2); S4A(0, 1, 0, tt + 2);
    S4A(0, 0, 1, tt + 2); S4A(0, 1, 1, tt + 2);
    WAIT_LGKM8();
    BAR(); WAIT_LGKM0();
    MFMA4(0);
    BAR();
    L4A(1, 1);
    S4B(1, 0, 0, tt + 3); S4B(1, 1, 0, tt + 3);
    S4B(1, 0, 1, tt + 3); S4B(1, 1, 1, tt + 3);
    WAIT_VM(4);
    BAR(); WAIT_LGKM0();
    MFMA4(1);
    BAR();
  }

  const int rb4 = (lane >> 4) * 4;
  const int wm = (w4 >> 1) * 64, wn = (w4 & 1) * 64;
#pragma unroll
  for (int mf = 0; mf < 4; ++mf) {
#pragma unroll
    for (int nf = 0; nf < 4; ++nf) {
      const int gm0 = m0 + wm + mf * 16 + rb4;
      const int gn = n0 + wn + nf * 16 + fr;
#pragma unroll
      for (int r = 0; r < 4; ++r) {
        const size_t idx = (size_t)z * sC + (size_t)(gm0 + r) * ldc + gn;
        O0[idx] = acc[mf][nf][r] + xres[idx];
      }
    }
  }
}

// One launch for all prep: 4 transposes, 3 straight converts, conv pack,
// rmsnorm.
__global__ __launch_bounds__(256) void prep_k(
    const float* __restrict__ up_w, const float* __restrict__ gate_w,
    const float* __restrict__ down_w, const float* __restrict__ wq,
    const float* __restrict__ wk, const float* __restrict__ wv,
    const float* __restrict__ wo, const float* __restrict__ conv_w,
    const float* __restrict__ x, const float* __restrict__ norm_w,
    ushort* __restrict__ ugw, ushort* __restrict__ down_wT,
    ushort* __restrict__ wq_bf, ushort* __restrict__ wk_bf,
    ushort* __restrict__ wv_bf, ushort* __restrict__ wo_T,
    ushort* __restrict__ cwT, ushort* __restrict__ nrm) {
  const int bid = blockIdx.x;
  const int t = threadIdx.x;
  if (bid < 7168) {  // transposes: fp32 [R][C] -> bf16 [C][R]
    const float* src; ushort* dst; int R, C, idx;
    if (bid < 2048)      { src = up_w;   dst = ugw;               R = 1024; C = 2048; idx = bid; }
    else if (bid < 4096) { src = gate_w; dst = ugw + 2048 * 1024; R = 1024; C = 2048; idx = bid - 2048; }
    else if (bid < 6144) { src = down_w; dst = down_wT;           R = 2048; C = 1024; idx = bid - 4096; }
    else                 { src = wo;     dst = wo_T;              R = 1024; C = 1024; idx = bid - 6144; }
    __shared__ float tile[32][33];
    const int tx = t & 31, ty = t >> 5;
    const int tilesx = C >> 5;
    const int c0 = (idx % tilesx) * 32, r0 = (idx / tilesx) * 32;
#pragma unroll
    for (int i = 0; i < 4; ++i)
      tile[ty + i * 8][tx] = src[(size_t)(r0 + ty + i * 8) * C + c0 + tx];
    __syncthreads();
#pragma unroll
    for (int i = 0; i < 4; ++i)
      dst[(size_t)(c0 + ty + i * 8) * R + r0 + tx] = f2bf(tile[tx][ty + i * 8]);
  } else if (bid < 10240) {  // straight converts wq/wk/wv
    const int seg = (bid - 7168) >> 10;
    const int idx = (bid - 7168) & 1023;
    const float* src = (seg == 0) ? wq : (seg == 1) ? wk : wv;
    ushort* dst = (seg == 0) ? wq_bf : (seg == 1) ? wk_bf : wv_bf;
    const size_t e = (size_t)idx * 1024 + t * 4;
    const float4 v = *(const float4*)(src + e);
    ushort4 r;
    r.x = f2bf(v.x); r.y = f2bf(v.y); r.z = f2bf(v.z); r.w = f2bf(v.w);
    *(ushort4*)(dst + e) = r;
  } else if (bid < 10248) {  // conv_w [DI][4] -> cwT [4][DI]
    const int c = (bid - 10240) * 256 + t;
    const float4 v = *(const float4*)(conv_w + c * 4);
    cwT[0 * DIc + c] = f2bf(v.x);
    cwT[1 * DIc + c] = f2bf(v.y);
    cwT[2 * DIc + c] = f2bf(v.z);
    cwT[3 * DIc + c] = f2bf(v.w);
  } else {  // rmsnorm rows
    const int row = bid - 10248;
    const float* xr = x + (size_t)row * Dd;
    const float4 v = *(const float4*)(xr + t * 4);
    float ss = v.x * v.x + v.y * v.y + v.z * v.z + v.w * v.w;
#pragma unroll
    for (int m = 32; m; m >>= 1) ss += __shfl_xor(ss, m);
    __shared__ float red[4];
    if ((t & 63) == 0) red[t >> 6] = ss;
    __syncthreads();
    const float total = red[0] + red[1] + red[2] + red[3];
    const float rs = rsqrtf(total * (1.f / (float)Dd) + 1e-6f);
    const float4 wt = *(const float4*)(norm_w + t * 4);
    ushort4 r;
    r.x = f2bf(v.x * rs * wt.x); r.y = f2bf(v.y * rs * wt.y);
    r.z = f2bf(v.z * rs * wt.z); r.w = f2bf(v.w * rs * wt.w);
    *(ushort4*)(nrm + (size_t)row * Dd + t * 4) = r;
  }
}

// bid<256: 256-thread m97-style 128x64 weight-product GEMM blocks
//   (WsT = wk@wq^T, Wv2T = wo^T@wv^T; 8 m-tiles x 16 n-tiles per product).
// bid>=256: conv: combined = silu(conv(up)+cb)*silu(gate), 8ch x 8t/thread.
__global__ __launch_bounds__(256) void conv_gate_k(
    const ushort* __restrict__ ug, const ushort* __restrict__ cwT,
    const float* __restrict__ cb, ushort* __restrict__ o,
    const ushort* __restrict__ wk_bf, const ushort* __restrict__ wq_bf,
    const ushort* __restrict__ wo_T, const ushort* __restrict__ wv_bf,
    ushort* __restrict__ WsT, ushort* __restrict__ Wv2T) {
  const int bid = blockIdx.x;
  const int t = threadIdx.x;
  if (bid < 256) {
    __shared__ ushort lds[6144];  // As [128][32] | Bs [64][32]
    ushort* As = lds;
    ushort* Bs = lds + 4096;
    const int oo = bid >> 7, lid = bid & 127;
    const int m0 = (lid >> 4) * 128, n0 = (lid & 15) * 64;
    const ushort* A = (oo ? wo_T : wk_bf) + (size_t)m0 * 1024;
    const ushort* B = (oo ? wv_bf : wq_bf) + (size_t)n0 * 1024;
    ushort* C = oo ? Wv2T : WsT;
    const int lane = t & 63, wave = t >> 6;
    const int wm = (wave >> 1) * 64, wn = (wave & 1) * 32;
    const int fr = lane & 15, kg = (lane >> 4) * 8;
    const int srow = wave * 16 + (lane >> 2), scol = (lane & 3) * 8;
    f32x4 acc[4][2] = {};
    for (int k0 = 0; k0 < 1024; k0 += 32) {
#pragma unroll
      for (int p = 0; p < 2; ++p)
        __builtin_amdgcn_global_load_lds(
            (const __attribute__((address_space(1))) void*)
                (A + (size_t)(srow + p * 64) * 1024 + k0 + scol),
            (__attribute__((address_space(3))) void*)(As + (p * 4 + wave) * 512),
            16, 0, 0);
      __builtin_amdgcn_global_load_lds(
          (const __attribute__((address_space(1))) void*)
              (B + (size_t)srow * 1024 + k0 + scol),
          (__attribute__((address_space(3))) void*)(Bs + wave * 512),
          16, 0, 0);
      __syncthreads();
      bf16x8 af[4], bv[2];
#pragma unroll
      for (int i = 0; i < 4; ++i)
        af[i] = *(const bf16x8*)&As[(wm + i * 16 + fr) * 32 + kg];
#pragma unroll
      for (int n = 0; n < 2; ++n)
        bv[n] = *(const bf16x8*)&Bs[(wn + n * 16 + fr) * 32 + kg];
#pragma unroll
      for (int mi = 0; mi < 4; ++mi)
#pragma unroll
        for (int ni = 0; ni < 2; ++ni)
          acc[mi][ni] = __builtin_amdgcn_mfma_f32_16x16x32_bf16(
              af[mi], bv[ni], acc[mi][ni], 0, 0, 0);
      __syncthreads();
    }
    const int rb = (lane >> 4) * 4;
#pragma unroll
    for (int mi = 0; mi < 4; ++mi)
#pragma unroll
      for (int ni = 0; ni < 2; ++ni)
#pragma unroll
        for (int r = 0; r < 4; ++r)
          C[(size_t)(m0 + wm + mi * 16 + rb + r) * 1024 + n0 + wn + ni * 16 + fr] =
              f2bf(acc[mi][ni][r]);
    return;
  }

  const int cbid = bid - 256;
  const int cg = t & 31;
  const int ts = t >> 5;
  const int cblk = cbid & 7;
  const int rblk = cbid >> 3;
  const int c = cblk * 256 + cg * 8;
  const int row0 = rblk * 64 + ts * 8;

  u16x8 w[4];
#pragma unroll
  for (int k = 0; k < 4; ++k) w[k] = *(const u16x8*)&cwT[k * DIc + c];
  float wb[8];
  *(float4*)&wb[0] = *(const float4*)(cb + c);
  *(float4*)&wb[4] = *(const float4*)(cb + c + 4);

  u16x8 h3, h2, h1;
  if ((row0 & (Ll - 1)) == 0) {
    h3 = (u16x8){}; h2 = (u16x8){}; h1 = (u16x8){};
  } else {
    h3 = *(const u16x8*)&ug[(size_t)(row0 - 3) * 4096 + c];
    h2 = *(const u16x8*)&ug[(size_t)(row0 - 2) * 4096 + c];
    h1 = *(const u16x8*)&ug[(size_t)(row0 - 1) * 4096 + c];
  }

#pragma unroll
  for (int i = 0; i < 8; ++i) {
    const size_t rbase = (size_t)(row0 + i) * 4096;
    const u16x8 h0 = *(const u16x8*)&ug[rbase + c];
    const u16x8 g  = *(const u16x8*)&ug[rbase + 2048 + c];
    u16x8 ov;
#pragma unroll
    for (int j = 0; j < 8; ++j) {
      float acc = wb[j];
      acc += bf2f(w[0][j]) * bf2f(h3[j]);
      acc += bf2f(w[1][j]) * bf2f(h2[j]);
      acc += bf2f(w[2][j]) * bf2f(h1[j]);
      acc += bf2f(w[3][j]) * bf2f(h0[j]);
      ov[j] = f2bf(silu(acc) * silu(bf2f(g[j])));
    }
    *(u16x8*)&o[(size_t)(row0 + i) * DIc + c] = ov;
    h3 = h2; h2 = h1; h1 = h0;
  }
}

extern "C" void kernel_launch(void* const* d_in, const int* in_sizes, int n_in,
                              void* d_out, int out_size, void* d_ws,
                              size_t ws_size, hipStream_t stream) {
  const float* x      = (const float*)d_in[0];
  const float* norm_w = (const float*)d_in[1];
  const float* up_w   = (const float*)d_in[2];
  const float* up_b   = (const float*)d_in[3];
  const float* gate_w = (const float*)d_in[4];
  const float* gate_b = (const float*)d_in[5];
  const float* down_w = (const float*)d_in[6];
  const float* down_b = (const float*)d_in[7];
  const float* conv_w = (const float*)d_in[8];
  const float* conv_b = (const float*)d_in[9];
  const float* wq     = (const float*)d_in[10];
  const float* wk     = (const float*)d_in[11];
  const float* wv     = (const float*)d_in[12];
  const float* wo     = (const float*)d_in[13];
  const float* decay  = (const float*)d_in[14];
  float* out = (float*)d_out;
  char* w8 = (char*)d_ws;

  const size_t MiB = 1u << 20;
  ushort* nrm      = (ushort*)(w8 + 0 * MiB);    // 16: normed, later D (down-out)
  ushort* ug       = (ushort*)(w8 + 16 * MiB);   // 64: up|gate [8192][4096]
  ushort* S        = (ushort*)(w8 + 16 * MiB);   // 32 (aliases ug; disjoint life)
  ushort* combined = (ushort*)(w8 + 80 * MiB);   // 32
  ushort* G        = (ushort*)(w8 + 112 * MiB);  // 16: G = D @ W_qk
  ushort* vT       = (ushort*)(w8 + 144 * MiB);  // 16: v'T[b][d][t]
  ushort* ugw      = (ushort*)(w8 + 176 * MiB);  // 8: [4096][1024]
  ushort* down_wT  = (ushort*)(w8 + 184 * MiB);  // 4: [1024][2048]
  ushort* wq_bf    = (ushort*)(w8 + 188 * MiB);  // 2 (raw row-major bf16)
  ushort* wk_bf    = (ushort*)(w8 + 190 * MiB);  // 2
  ushort* wv_bf    = (ushort*)(w8 + 192 * MiB);  // 2
  ushort* wo_T     = (ushort*)(w8 + 194 * MiB);  // 2
  ushort* WsT      = (ushort*)(w8 + 196 * MiB);  // 2: wk @ wq^T
  ushort* Wv2T     = (ushort*)(w8 + 198 * MiB);  // 2: wo^T @ wv^T (contig w/ WsT)
  ushort* cwT      = (ushort*)(w8 + 200 * MiB);  // 16 KiB

  prep_k<<<18440, 256, 0, stream>>>(up_w, gate_w, down_w, wq, wk, wv, wo,
                                    conv_w, x, norm_w,
                                    ugw, down_wT, wq_bf, wk_bf, wv_bf, wo_T,
                                    cwT, nrm);

  // ug = normed @ [up_w|gate_w] + biases  (512 blocks = 2 rounds)
  gemm8_k<EP_UG, 256><<<dim3(16, 32), 512, 0, stream>>>(
      nrm, ugw, ug, up_b, gate_b,
      1024, 1024, 1024, 4096, 0, 0, 0, nullptr);

  // 256 weight-product GEMM blocks (128x64 tiles) + 1024 conv blocks
  conv_gate_k<<<1280, 256, 0, stream>>>(ug, cwT, conv_b, combined,
                                        wk_bf, wq_bf, wo_T, wv_bf, WsT, Wv2T);

  // D = combined @ down_w + b  (256 blocks = 1 round)
  gemm8_k<EP_DOWN, 128><<<dim3(4, 64), 512, 0, stream>>>(
      combined, down_wT, nrm, down_b, nullptr,
      2048, 2048, 2048, 1024, 0, 0, 0, nullptr);

  // [G | v'] = D @ [WsT | Wv2T]^T  (256 blocks = 1 round, BM=256)
  gemm8_k<EP_GV, 256><<<dim3(8, 32), 512, 0, stream>>>(
      nrm, WsT, G, nullptr, nullptr,
      1024, 1024, 1024, 1024, 0, 0, 0, vT);

  // S = tril(G @ D^T) * d^(t-s)  (BK=32 4-wave, 16 KiB LDS, ~6 blocks/CU:
  // all 544 tril tiles co-resident -> no scheduling tail)
  decay_k<<<dim3(16, 16, Bb), 256, 0, stream>>>(G, nrm, S, decay);

  // out = x + S @ v'  (4-wave 64 KiB, 512 blocks, complementary-K pairing)
  yo_k<<<dim3(8, 64), 256, 0, stream>>>(
      S, vT, out, x,
      2048, 2048, 1024, (long)Ll * Ll, LD, LD);
}

// Round 12
// 271.051 us; speedup vs baseline: 1.0601x; 1.0601x over previous
//
#include <hip/hip_runtime.h>

// Fused block, all-bf16 dataflow. GEMMs: 8-phase 512-thread template
// (BM=256/128, BN=256, BK=64, st_16x32 LDS swizzle, counted vmcnt, setprio);
// 4-wave 256-thread variant for the attention pair (DECAY tril tiles, YO
// complementary-K pairing, 2 blocks/CU). Algebraic folds: S = (D@W_qk)@D^T
// (W_qk = wq wk^T), wo folded into v: v' = D@(wv wo), out = x + S@v'.
// Weight-product GEMMs ride as 256 leading 128x64 blocks in conv_gate.
// (R12 = revert to the measured-best R10 configuration.)

typedef __bf16 bf16x8 __attribute__((ext_vector_type(8)));
typedef unsigned short u16x8 __attribute__((ext_vector_type(8)));
typedef float f32x4 __attribute__((ext_vector_type(4)));

constexpr int Bb = 4, Ll = 2048, Dd = 1024, DIc = 2048;
constexpr long LD  = (long)Ll * Dd;   // 2,097,152
constexpr long BLD = (long)Bb * LD;   // 8,388,608

static __device__ __forceinline__ unsigned short f2bf(float f) {
  unsigned u = __builtin_bit_cast(unsigned, f);
  u += 0x7fffu + ((u >> 16) & 1u);  // RNE
  return (unsigned short)(u >> 16);
}
static __device__ __forceinline__ float bf2f(unsigned short u) {
  return __builtin_bit_cast(float, (unsigned)u << 16);
}
static __device__ __forceinline__ float silu(float g) {
  return g / (1.f + __expf(-g));
}

enum { EP_UG = 0, EP_DOWN, EP_GV, EP_DECAY, EP_YO };

#define STAGE_A(DBUF, MG, KH, TILE) {                                          \
    const int kt_ = ((TILE) < NTm1 ? (TILE) : NTm1);                           \
    __builtin_amdgcn_global_load_lds(                                          \
      (const __attribute__((address_space(1))) void*)                          \
        (Ag + (size_t)(aRow + (MG)*64) * lda + kt_*64 + (KH)*32 + aCol),       \
      (__attribute__((address_space(3))) void*)                                \
        (lds + (DBUF)*ADB + (KH)*AKH + (aRb + (MG)*4)*512), 16, 0, 0); }

#define STAGE_B(DBUF, NH, KH, TILE) {                                          \
    const int kt_ = ((TILE) < NTm1 ? (TILE) : NTm1);                           \
    __builtin_amdgcn_global_load_lds(                                          \
      (const __attribute__((address_space(1))) void*)                          \
        (Bg + (size_t)(bRow + (NH)*128) * ldb + kt_*64 + (KH)*32 + aCol),      \
      (__attribute__((address_space(3))) void*)                                \
        (lds + BOFF + (DBUF)*16384 + (KH)*8192 + ((NH)*8 + w)*512), 16, 0, 0); }

#define LOAD_A(DBUF, KS, MG) {                                                 \
  _Pragma("unroll") for (int j_ = 0; j_ < 4; ++j_)                             \
    af[j_] = *(const bf16x8*)&lds[(DBUF)*ADB + (KS)*AKH +                      \
        (aRdBase + (MG)*4 + j_)*512 + fr*32 + cph]; }

#define LOAD_B(DBUF, KS) {                                                     \
  _Pragma("unroll") for (int n_ = 0; n_ < 4; ++n_)                             \
    bfr[KS][n_] = *(const bf16x8*)&lds[BOFF + (DBUF)*16384 + (KS)*8192 +       \
        (bRb + n_)*512 + fr*32 + cph]; }

#define MFMA_PH(KS, MG) {                                                      \
  __builtin_amdgcn_s_setprio(1);                                               \
  _Pragma("unroll") for (int j_ = 0; j_ < 4; ++j_)                             \
  _Pragma("unroll") for (int n_ = 0; n_ < 4; ++n_)                             \
    acc[(MG)*4 + j_][n_] = __builtin_amdgcn_mfma_f32_16x16x32_bf16(            \
        af[j_], bfr[KS][n_], acc[(MG)*4 + j_][n_], 0, 0, 0);                   \
  __builtin_amdgcn_s_setprio(0); }

#define BAR() __builtin_amdgcn_s_barrier()
#define WAIT_LGKM0() { asm volatile("s_waitcnt lgkmcnt(0)" ::: "memory");      \
                       __builtin_amdgcn_sched_barrier(0); }
#define WAIT_LGKM8() asm volatile("s_waitcnt lgkmcnt(8)" ::: "memory")
#define WAIT_VM(N) asm volatile("s_waitcnt vmcnt(" #N ")" ::: "memory")

template <int EPI, int BM>
__global__ __launch_bounds__(512, 2) void gemm8_k(
    const ushort* __restrict__ A, const ushort* __restrict__ Bm,
    void* __restrict__ O0, const float* __restrict__ bias,
    const float* __restrict__ bias2,
    int K, int lda, int ldb, int ldc,
    long sA, long sB, long sC,
    void* __restrict__ O1) {
  constexpr int MF = BM / 32;
  constexpr int ADB = BM * 64;
  constexpr int AKH = BM * 32;
  constexpr int BOFF = BM * 128;
  __shared__ ushort lds[BM == 256 ? 65536 : 49152];

  const int z = blockIdx.z;
  const int gx = gridDim.x;
  const int nwg = gx * gridDim.y;
  const int id = blockIdx.y * gx + blockIdx.x;
  const int chunk = nwg >> 3;
  const int swz = (id & 7) * chunk + (id >> 3);
  const int m0 = (swz / gx) * BM;
  const int n0 = (swz % gx) * 256;

  const int t = threadIdx.x;
  const int lane = t & 63;
  const int w = t >> 6;

  const ushort* Ag = A + (size_t)z * sA + (size_t)m0 * lda;
  const ushort* Bg = Bm + (size_t)z * sB + (size_t)n0 * ldb;

  const int NT = K >> 6;
  const int NTm1 = NT - 1;
  const int NI = NT >> 1;

  // stage-side: lane' pre-applies the st_16x32 swizzle
  const int lp = lane ^ (((lane >> 5) & 1) << 1);
  const int aCol = (lp & 3) * 8;
  const int bRow = (w >> 2) * 64 + (w & 3) * 16 + (lp >> 2);
  int aRow, aRb, aRdBase;
  if constexpr (BM == 256) {
    aRow = (w >> 2) * 128 + (w & 3) * 16 + (lp >> 2);
    aRb = (w >> 2) * 8 + (w & 3);
    aRdBase = (w >> 2) * 8;
  } else {
    aRow = w * 16 + (lp >> 2);
    aRb = w;
    aRdBase = (w >> 2) * 4;
  }
  // read-side
  const int fr = lane & 15;
  const int kg = (lane >> 4) * 8;
  const int cph = kg ^ (((fr >> 3) & 1) << 4);
  const int bRb = ((w & 3) >> 1) * 8 + ((w & 3) & 1) * 4;

  f32x4 acc[MF][4] = {};
  bf16x8 af[4], bfr[2][4];

  if constexpr (BM == 256) {
    STAGE_A(0, 0, 0, 0); STAGE_A(0, 0, 1, 0); STAGE_A(0, 1, 0, 0); STAGE_A(0, 1, 1, 0);
    STAGE_B(0, 0, 0, 0); STAGE_B(0, 0, 1, 0); STAGE_B(0, 1, 0, 0); STAGE_B(0, 1, 1, 0);
    STAGE_B(1, 0, 0, 1); STAGE_B(1, 0, 1, 1); STAGE_B(1, 1, 0, 1); STAGE_B(1, 1, 1, 1);
    STAGE_A(1, 0, 0, 1); STAGE_A(1, 0, 1, 1);
    WAIT_VM(6);
    BAR();
    for (int i = 0; i < NI; ++i) {
      const int tt = 2 * i;
      LOAD_B(0, 0); LOAD_B(0, 1); LOAD_A(0, 0, 0);
      STAGE_A(1, 1, 0, tt + 1); STAGE_A(1, 1, 1, tt + 1);
      WAIT_LGKM8();
      BAR(); WAIT_LGKM0();
      MFMA_PH(0, 0);
      BAR();
      LOAD_A(0, 0, 1);
      STAGE_B(0, 0, 0, tt + 2); STAGE_B(0, 1, 0, tt + 2);
      BAR(); WAIT_LGKM0();
      MFMA_PH(0, 1);
      BAR();
      LOAD_A(0, 1, 0);
      STAGE_B(0, 0, 1, tt + 2); STAGE_B(0, 1, 1, tt + 2);
      BAR(); WAIT_LGKM0();
      MFMA_PH(1, 0);
      BAR();
      LOAD_A(0, 1, 1);
      STAGE_A(0, 0, 0, tt + 2); STAGE_A(0, 0, 1, tt + 2);
      WAIT_VM(6);
      BAR(); WAIT_LGKM0();
      MFMA_PH(1, 1);
      BAR();
      LOAD_B(1, 0); LOAD_B(1, 1); LOAD_A(1, 0, 0);
      STAGE_A(0, 1, 0, tt + 2); STAGE_A(0, 1, 1, tt + 2);
      WAIT_LGKM8();
      BAR(); WAIT_LGKM0();
      MFMA_PH(0, 0);
      BAR();
      LOAD_A(1, 0, 1);
      STAGE_B(1, 0, 0, tt + 3); STAGE_B(1, 1, 0, tt + 3);
      BAR(); WAIT_LGKM0();
      MFMA_PH(0, 1);
      BAR();
      LOAD_A(1, 1, 0);
      STAGE_B(1, 0, 1, tt + 3); STAGE_B(1, 1, 1, tt + 3);
      BAR(); WAIT_LGKM0();
      MFMA_PH(1, 0);
      BAR();
      LOAD_A(1, 1, 1);
      STAGE_A(1, 0, 0, tt + 3); STAGE_A(1, 0, 1, tt + 3);
      WAIT_VM(6);
      BAR(); WAIT_LGKM0();
      MFMA_PH(1, 1);
      BAR();
    }
  } else {
    STAGE_A(0, 0, 0, 0); STAGE_A(0, 0, 1, 0);
    STAGE_B(0, 0, 0, 0); STAGE_B(0, 1, 0, 0); STAGE_B(0, 0, 1, 0); STAGE_B(0, 1, 1, 0);
    STAGE_B(1, 0, 0, 1); STAGE_B(1, 1, 0, 1); STAGE_B(1, 0, 1, 1); STAGE_B(1, 1, 1, 1);
    WAIT_VM(4);
    BAR();
    for (int i = 0; i < NI; ++i) {
      const int tt = 2 * i;
      LOAD_B(0, 0); LOAD_B(0, 1); LOAD_A(0, 0, 0);
      STAGE_A(1, 0, 0, tt + 1); STAGE_A(1, 0, 1, tt + 1);
      WAIT_LGKM8();
      BAR(); WAIT_LGKM0();
      MFMA_PH(0, 0);
      BAR();
      LOAD_A(0, 1, 0);
      STAGE_B(0, 0, 0, tt + 2); STAGE_B(0, 1, 0, tt + 2);
      STAGE_B(0, 0, 1, tt + 2); STAGE_B(0, 1, 1, tt + 2);
      WAIT_VM(4);
      BAR(); WAIT_LGKM0();
      MFMA_PH(1, 0);
      BAR();
      LOAD_B(1, 0); LOAD_B(1, 1); LOAD_A(1, 0, 0);
      STAGE_A(0, 0, 0, tt + 2); STAGE_A(0, 0, 1, tt + 2);
      WAIT_LGKM8();
      BAR(); WAIT_LGKM0();
      MFMA_PH(0, 0);
      BAR();
      LOAD_A(1, 1, 0);
      STAGE_B(1, 0, 0, tt + 3); STAGE_B(1, 1, 0, tt + 3);
      STAGE_B(1, 0, 1, tt + 3); STAGE_B(1, 1, 1, tt + 3);
      WAIT_VM(4);
      BAR(); WAIT_LGKM0();
      MFMA_PH(1, 0);
      BAR();
    }
  }

  // ---- epilogue ---- C/D: col=lane&15, row=(lane>>4)*4+reg
  const int rb4 = (lane >> 4) * 4;
  const int wm = (w >> 2) * (BM / 2), wn = (w & 3) * 64;

#pragma unroll
  for (int mf = 0; mf < MF; ++mf) {
#pragma unroll
    for (int nf = 0; nf < 4; ++nf) {
      const int gm0 = m0 + wm + mf * 16 + rb4;
      const int gn = n0 + wn + nf * 16 + fr;
      if constexpr (EPI == EP_GV) {
        if (gn < 1024) {  // G half: plain bf16
#pragma unroll
          for (int r = 0; r < 4; ++r)
            ((ushort*)O0)[(size_t)(gm0 + r) * 1024 + gn] = f2bf(acc[mf][nf][r]);
        } else {  // v' half: transposed write vT[b][d][t]
          const int d = gn - 1024, b = gm0 >> 11, ttp = gm0 & 2047;
          ushort4 w4;
          w4.x = f2bf(acc[mf][nf][0]); w4.y = f2bf(acc[mf][nf][1]);
          w4.z = f2bf(acc[mf][nf][2]); w4.w = f2bf(acc[mf][nf][3]);
          *(ushort4*)&((ushort*)O1)[(size_t)b * LD + (size_t)d * Ll + ttp] = w4;
        }
      } else {
#pragma unroll
        for (int r = 0; r < 4; ++r) {
          const int gm = gm0 + r;
          const size_t idx = (size_t)z * sC + (size_t)gm * ldc + gn;
          const float v = acc[mf][nf][r];
          if constexpr (EPI == EP_UG) {
            const float b = (gn < 2048) ? bias[gn] : bias2[gn - 2048];
            ((ushort*)O0)[idx] = f2bf(v + b);
          } else {  // EP_DOWN
            ((ushort*)O0)[idx] = f2bf(v + bias[gn]);
          }
        }
      }
    }
  }
}

// ---- 4-wave (256-thread) BM=128/BN=128 variant, 64 KiB LDS, 2 blocks/CU ----
#define S4A(DBUF, MG, KH, TILE) {                                              \
    const int kt_ = ((TILE) < NTm1 ? (TILE) : NTm1);                           \
    __builtin_amdgcn_global_load_lds(                                          \
      (const __attribute__((address_space(1))) void*)                          \
        (Ag + (size_t)(sRow + (MG)*64) * lda + kt_*64 + (KH)*32 + sCol),       \
      (__attribute__((address_space(3))) void*)                                \
        (lds + (DBUF)*8192 + (KH)*4096 + ((MG)*4 + w4)*512), 16, 0, 0); }

#define S4B(DBUF, NH, KH, TILE) {                                              \
    const int kt_ = ((TILE) < NTm1 ? (TILE) : NTm1);                           \
    __builtin_amdgcn_global_load_lds(                                          \
      (const __attribute__((address_space(1))) void*)                          \
        (Bg + (size_t)(sRow + (NH)*64) * ldb + kt_*64 + (KH)*32 + sCol),       \
      (__attribute__((address_space(3))) void*)                                \
        (lds + 16384 + (DBUF)*8192 + (KH)*4096 + ((NH)*4 + w4)*512), 16, 0, 0); }

#define L4A(DBUF, KS) {                                                        \
  _Pragma("unroll") for (int j_ = 0; j_ < 4; ++j_)                             \
    af[j_] = *(const bf16x8*)&lds[(DBUF)*8192 + (KS)*4096 +                    \
        (aRd + j_)*512 + fr*32 + cph]; }

#define L4B(DBUF, KS) {                                                        \
  _Pragma("unroll") for (int n_ = 0; n_ < 4; ++n_)                             \
    bfr[KS][n_] = *(const bf16x8*)&lds[16384 + (DBUF)*8192 + (KS)*4096 +       \
        (bRd + n_)*512 + fr*32 + cph]; }

#define MFMA4(KS) {                                                            \
  __builtin_amdgcn_s_setprio(1);                                               \
  _Pragma("unroll") for (int j_ = 0; j_ < 4; ++j_)                             \
  _Pragma("unroll") for (int n_ = 0; n_ < 4; ++n_)                             \
    acc[j_][n_] = __builtin_amdgcn_mfma_f32_16x16x32_bf16(                     \
        af[j_], bfr[KS][n_], acc[j_][n_], 0, 0, 0);                            \
  __builtin_amdgcn_s_setprio(0); }

template <int EPI>  // EP_DECAY or EP_YO
__global__ __launch_bounds__(256, 2) void gemm4_k(
    const ushort* __restrict__ A, const ushort* __restrict__ Bm,
    void* __restrict__ O0, const float* __restrict__ xres,
    const float* __restrict__ decayp,
    int K, int lda, int ldb, int ldc, long sA, long sB, long sC) {
  __shared__ ushort lds[32768];  // 64 KiB

  const int t = threadIdx.x;
  const int lane = t & 63;
  const int w4 = t >> 6;

  int z, m0, n0;
  if constexpr (EPI == EP_YO) {
    // grid (8,64) flat; id and id+256 -> complementary m-tiles (i, 15-i)
    const int id = blockIdx.y * gridDim.x + blockIdx.x;
    const int half = id >> 8;
    const int u = id & 255;
    const int nt = u & 7;
    const int rem = u >> 3;  // 0..31
    z = rem >> 3;
    const int i8 = rem & 7;
    const int mt = half ? (15 - i8) : i8;
    m0 = mt * 128;
    n0 = nt * 128;
  } else {  // EP_DECAY: grid (16,16,4), XCD swizzle + tril filter
    z = blockIdx.z;
    const int gx = gridDim.x;
    const int nwg = gx * gridDim.y;
    const int id = blockIdx.y * gx + blockIdx.x;
    const int chunk = nwg >> 3;
    const int swz = (id & 7) * chunk + (id >> 3);
    m0 = (swz / gx) * 128;
    n0 = (swz % gx) * 128;
    if (n0 > m0) return;  // above diagonal: never read by YO (K-clamp)
  }

  const ushort* Ag = A + (size_t)z * sA + (size_t)m0 * lda;
  const ushort* Bg = Bm + (size_t)z * sB + (size_t)n0 * ldb;

  int Kend = K;
  if constexpr (EPI == EP_YO) Kend = m0 + 128;
  const int NT = Kend >> 6;
  const int NTm1 = NT - 1;
  const int NI = NT >> 1;

  const int lp = lane ^ (((lane >> 5) & 1) << 1);
  const int sRow = w4 * 16 + (lp >> 2);
  const int sCol = (lp & 3) * 8;
  const int fr = lane & 15;
  const int kg = (lane >> 4) * 8;
  const int cph = kg ^ (((fr >> 3) & 1) << 4);
  const int aRd = (w4 >> 1) * 4;  // wm = (w4>>1)*64
  const int bRd = (w4 & 1) * 4;   // wn = (w4&1)*64

  f32x4 acc[4][4] = {};
  bf16x8 af[4], bfr[2][4];

  // prologue: A0(4) + B0(4) + B1(4); vmcnt(4) leaves B1 in flight
  S4A(0, 0, 0, 0); S4A(0, 1, 0, 0); S4A(0, 0, 1, 0); S4A(0, 1, 1, 0);
  S4B(0, 0, 0, 0); S4B(0, 1, 0, 0); S4B(0, 0, 1, 0); S4B(0, 1, 1, 0);
  S4B(1, 0, 0, 1); S4B(1, 1, 0, 1); S4B(1, 0, 1, 1); S4B(1, 1, 1, 1);
  WAIT_VM(4);
  BAR();
  for (int i = 0; i < NI; ++i) {
    const int tt = 2 * i;
    L4B(0, 0); L4B(0, 1); L4A(0, 0);
    S4A(1, 0, 0, tt + 1); S4A(1, 1, 0, tt + 1);
    S4A(1, 0, 1, tt + 1); S4A(1, 1, 1, tt + 1);
    WAIT_LGKM8();
    BAR(); WAIT_LGKM0();
    MFMA4(0);
    BAR();
    L4A(0, 1);
    S4B(0, 0, 0, tt + 2); S4B(0, 1, 0, tt + 2);
    S4B(0, 0, 1, tt + 2); S4B(0, 1, 1, tt + 2);
    WAIT_VM(4);
    BAR(); WAIT_LGKM0();
    MFMA4(1);
    BAR();
    L4B(1, 0); L4B(1, 1); L4A(1, 0);
    S4A(0, 0, 0, tt + 2); S4A(0, 1, 0, tt + 2);
    S4A(0, 0, 1, tt + 2); S4A(0, 1, 1, tt + 2);
    WAIT_LGKM8();
    BAR(); WAIT_LGKM0();
    MFMA4(0);
    BAR();
    L4A(1, 1);
    S4B(1, 0, 0, tt + 3); S4B(1, 1, 0, tt + 3);
    S4B(1, 0, 1, tt + 3); S4B(1, 1, 1, tt + 3);
    WAIT_VM(4);
    BAR(); WAIT_LGKM0();
    MFMA4(1);
    BAR();
  }

  // ---- epilogue ----
  const int rb4 = (lane >> 4) * 4;
  const int wm = (w4 >> 1) * 64, wn = (w4 & 1) * 64;
  float logd = 0.f;
  if constexpr (EPI == EP_DECAY) logd = __logf(decayp[0]);

#pragma unroll
  for (int mf = 0; mf < 4; ++mf) {
#pragma unroll
    for (int nf = 0; nf < 4; ++nf) {
      const int gm0 = m0 + wm + mf * 16 + rb4;
      const int gn = n0 + wn + nf * 16 + fr;
#pragma unroll
      for (int r = 0; r < 4; ++r) {
        const int gm = gm0 + r;
        const size_t idx = (size_t)z * sC + (size_t)gm * ldc + gn;
        const float v = acc[mf][nf][r];
        if constexpr (EPI == EP_DECAY) {
          ((ushort*)O0)[idx] =
              (gn <= gm) ? f2bf(v * __expf((float)(gm - gn) * logd)) : (ushort)0;
        } else {  // EP_YO: out = x + S@v'
          ((float*)O0)[idx] = v + xres[idx];
        }
      }
    }
  }
}

// One launch for all prep: 4 transposes, 3 straight converts, conv pack,
// rmsnorm.
__global__ __launch_bounds__(256) void prep_k(
    const float* __restrict__ up_w, const float* __restrict__ gate_w,
    const float* __restrict__ down_w, const float* __restrict__ wq,
    const float* __restrict__ wk, const float* __restrict__ wv,
    const float* __restrict__ wo, const float* __restrict__ conv_w,
    const float* __restrict__ x, const float* __restrict__ norm_w,
    ushort* __restrict__ ugw, ushort* __restrict__ down_wT,
    ushort* __restrict__ wq_bf, ushort* __restrict__ wk_bf,
    ushort* __restrict__ wv_bf, ushort* __restrict__ wo_T,
    ushort* __restrict__ cwT, ushort* __restrict__ nrm) {
  const int bid = blockIdx.x;
  const int t = threadIdx.x;
  if (bid < 7168) {  // transposes: fp32 [R][C] -> bf16 [C][R]
    const float* src; ushort* dst; int R, C, idx;
    if (bid < 2048)      { src = up_w;   dst = ugw;               R = 1024; C = 2048; idx = bid; }
    else if (bid < 4096) { src = gate_w; dst = ugw + 2048 * 1024; R = 1024; C = 2048; idx = bid - 2048; }
    else if (bid < 6144) { src = down_w; dst = down_wT;           R = 2048; C = 1024; idx = bid - 4096; }
    else                 { src = wo;     dst = wo_T;              R = 1024; C = 1024; idx = bid - 6144; }
    __shared__ float tile[32][33];
    const int tx = t & 31, ty = t >> 5;
    const int tilesx = C >> 5;
    const int c0 = (idx % tilesx) * 32, r0 = (idx / tilesx) * 32;
#pragma unroll
    for (int i = 0; i < 4; ++i)
      tile[ty + i * 8][tx] = src[(size_t)(r0 + ty + i * 8) * C + c0 + tx];
    __syncthreads();
#pragma unroll
    for (int i = 0; i < 4; ++i)
      dst[(size_t)(c0 + ty + i * 8) * R + r0 + tx] = f2bf(tile[tx][ty + i * 8]);
  } else if (bid < 10240) {  // straight converts wq/wk/wv
    const int seg = (bid - 7168) >> 10;
    const int idx = (bid - 7168) & 1023;
    const float* src = (seg == 0) ? wq : (seg == 1) ? wk : wv;
    ushort* dst = (seg == 0) ? wq_bf : (seg == 1) ? wk_bf : wv_bf;
    const size_t e = (size_t)idx * 1024 + t * 4;
    const float4 v = *(const float4*)(src + e);
    ushort4 r;
    r.x = f2bf(v.x); r.y = f2bf(v.y); r.z = f2bf(v.z); r.w = f2bf(v.w);
    *(ushort4*)(dst + e) = r;
  } else if (bid < 10248) {  // conv_w [DI][4] -> cwT [4][DI]
    const int c = (bid - 10240) * 256 + t;
    const float4 v = *(const float4*)(conv_w + c * 4);
    cwT[0 * DIc + c] = f2bf(v.x);
    cwT[1 * DIc + c] = f2bf(v.y);
    cwT[2 * DIc + c] = f2bf(v.z);
    cwT[3 * DIc + c] = f2bf(v.w);
  } else {  // rmsnorm rows
    const int row = bid - 10248;
    const float* xr = x + (size_t)row * Dd;
    const float4 v = *(const float4*)(xr + t * 4);
    float ss = v.x * v.x + v.y * v.y + v.z * v.z + v.w * v.w;
#pragma unroll
    for (int m = 32; m; m >>= 1) ss += __shfl_xor(ss, m);
    __shared__ float red[4];
    if ((t & 63) == 0) red[t >> 6] = ss;
    __syncthreads();
    const float total = red[0] + red[1] + red[2] + red[3];
    const float rs = rsqrtf(total * (1.f / (float)Dd) + 1e-6f);
    const float4 wt = *(const float4*)(norm_w + t * 4);
    ushort4 r;
    r.x = f2bf(v.x * rs * wt.x); r.y = f2bf(v.y * rs * wt.y);
    r.z = f2bf(v.z * rs * wt.z); r.w = f2bf(v.w * rs * wt.w);
    *(ushort4*)(nrm + (size_t)row * Dd + t * 4) = r;
  }
}

// bid<256: 256-thread m97-style 128x64 weight-product GEMM blocks
//   (WsT = wk@wq^T, Wv2T = wo^T@wv^T; 8 m-tiles x 16 n-tiles per product).
// bid>=256: conv: combined = silu(conv(up)+cb)*silu(gate), 8ch x 8t/thread.
__global__ __launch_bounds__(256) void conv_gate_k(
    const ushort* __restrict__ ug, const ushort* __restrict__ cwT,
    const float* __restrict__ cb, ushort* __restrict__ o,
    const ushort* __restrict__ wk_bf, const ushort* __restrict__ wq_bf,
    const ushort* __restrict__ wo_T, const ushort* __restrict__ wv_bf,
    ushort* __restrict__ WsT, ushort* __restrict__ Wv2T) {
  const int bid = blockIdx.x;
  const int t = threadIdx.x;
  if (bid < 256) {
    __shared__ ushort lds[6144];  // As [128][32] | Bs [64][32]
    ushort* As = lds;
    ushort* Bs = lds + 4096;
    const int oo = bid >> 7, lid = bid & 127;
    const int m0 = (lid >> 4) * 128, n0 = (lid & 15) * 64;
    const ushort* A = (oo ? wo_T : wk_bf) + (size_t)m0 * 1024;
    const ushort* B = (oo ? wv_bf : wq_bf) + (size_t)n0 * 1024;
    ushort* C = oo ? Wv2T : WsT;
    const int lane = t & 63, wave = t >> 6;
    const int wm = (wave >> 1) * 64, wn = (wave & 1) * 32;
    const int fr = lane & 15, kg = (lane >> 4) * 8;
    const int srow = wave * 16 + (lane >> 2), scol = (lane & 3) * 8;
    f32x4 acc[4][2] = {};
    for (int k0 = 0; k0 < 1024; k0 += 32) {
#pragma unroll
      for (int p = 0; p < 2; ++p)
        __builtin_amdgcn_global_load_lds(
            (const __attribute__((address_space(1))) void*)
                (A + (size_t)(srow + p * 64) * 1024 + k0 + scol),
            (__attribute__((address_space(3))) void*)(As + (p * 4 + wave) * 512),
            16, 0, 0);
      __builtin_amdgcn_global_load_lds(
          (const __attribute__((address_space(1))) void*)
              (B + (size_t)srow * 1024 + k0 + scol),
          (__attribute__((address_space(3))) void*)(Bs + wave * 512),
          16, 0, 0);
      __syncthreads();
      bf16x8 af[4], bv[2];
#pragma unroll
      for (int i = 0; i < 4; ++i)
        af[i] = *(const bf16x8*)&As[(wm + i * 16 + fr) * 32 + kg];
#pragma unroll
      for (int n = 0; n < 2; ++n)
        bv[n] = *(const bf16x8*)&Bs[(wn + n * 16 + fr) * 32 + kg];
#pragma unroll
      for (int mi = 0; mi < 4; ++mi)
#pragma unroll
        for (int ni = 0; ni < 2; ++ni)
          acc[mi][ni] = __builtin_amdgcn_mfma_f32_16x16x32_bf16(
              af[mi], bv[ni], acc[mi][ni], 0, 0, 0);
      __syncthreads();
    }
    const int rb = (lane >> 4) * 4;
#pragma unroll
    for (int mi = 0; mi < 4; ++mi)
#pragma unroll
      for (int ni = 0; ni < 2; ++ni)
#pragma unroll
        for (int r = 0; r < 4; ++r)
          C[(size_t)(m0 + wm + mi * 16 + rb + r) * 1024 + n0 + wn + ni * 16 + fr] =
              f2bf(acc[mi][ni][r]);
    return;
  }

  const int cbid = bid - 256;
  const int cg = t & 31;
  const int ts = t >> 5;
  const int cblk = cbid & 7;
  const int rblk = cbid >> 3;
  const int c = cblk * 256 + cg * 8;
  const int row0 = rblk * 64 + ts * 8;

  u16x8 w[4];
#pragma unroll
  for (int k = 0; k < 4; ++k) w[k] = *(const u16x8*)&cwT[k * DIc + c];
  float wb[8];
  *(float4*)&wb[0] = *(const float4*)(cb + c);
  *(float4*)&wb[4] = *(const float4*)(cb + c + 4);

  u16x8 h3, h2, h1;
  if ((row0 & (Ll - 1)) == 0) {
    h3 = (u16x8){}; h2 = (u16x8){}; h1 = (u16x8){};
  } else {
    h3 = *(const u16x8*)&ug[(size_t)(row0 - 3) * 4096 + c];
    h2 = *(const u16x8*)&ug[(size_t)(row0 - 2) * 4096 + c];
    h1 = *(const u16x8*)&ug[(size_t)(row0 - 1) * 4096 + c];
  }

#pragma unroll
  for (int i = 0; i < 8; ++i) {
    const size_t rbase = (size_t)(row0 + i) * 4096;
    const u16x8 h0 = *(const u16x8*)&ug[rbase + c];
    const u16x8 g  = *(const u16x8*)&ug[rbase + 2048 + c];
    u16x8 ov;
#pragma unroll
    for (int j = 0; j < 8; ++j) {
      float acc = wb[j];
      acc += bf2f(w[0][j]) * bf2f(h3[j]);
      acc += bf2f(w[1][j]) * bf2f(h2[j]);
      acc += bf2f(w[2][j]) * bf2f(h1[j]);
      acc += bf2f(w[3][j]) * bf2f(h0[j]);
      ov[j] = f2bf(silu(acc) * silu(bf2f(g[j])));
    }
    *(u16x8*)&o[(size_t)(row0 + i) * DIc + c] = ov;
    h3 = h2; h2 = h1; h1 = h0;
  }
}

extern "C" void kernel_launch(void* const* d_in, const int* in_sizes, int n_in,
                              void* d_out, int out_size, void* d_ws,
                              size_t ws_size, hipStream_t stream) {
  const float* x      = (const float*)d_in[0];
  const float* norm_w = (const float*)d_in[1];
  const float* up_w   = (const float*)d_in[2];
  const float* up_b   = (const float*)d_in[3];
  const float* gate_w = (const float*)d_in[4];
  const float* gate_b = (const float*)d_in[5];
  const float* down_w = (const float*)d_in[6];
  const float* down_b = (const float*)d_in[7];
  const float* conv_w = (const float*)d_in[8];
  const float* conv_b = (const float*)d_in[9];
  const float* wq     = (const float*)d_in[10];
  const float* wk     = (const float*)d_in[11];
  const float* wv     = (const float*)d_in[12];
  const float* wo     = (const float*)d_in[13];
  const float* decay  = (const float*)d_in[14];
  float* out = (float*)d_out;
  char* w8 = (char*)d_ws;

  const size_t MiB = 1u << 20;
  ushort* nrm      = (ushort*)(w8 + 0 * MiB);    // 16: normed, later D (down-out)
  ushort* ug       = (ushort*)(w8 + 16 * MiB);   // 64: up|gate [8192][4096]
  ushort* S        = (ushort*)(w8 + 16 * MiB);   // 32 (aliases ug; disjoint life)
  ushort* combined = (ushort*)(w8 + 80 * MiB);   // 32
  ushort* G        = (ushort*)(w8 + 112 * MiB);  // 16: G = D @ W_qk
  ushort* vT       = (ushort*)(w8 + 144 * MiB);  // 16: v'T[b][d][t]
  ushort* ugw      = (ushort*)(w8 + 176 * MiB);  // 8: [4096][1024]
  ushort* down_wT  = (ushort*)(w8 + 184 * MiB);  // 4: [1024][2048]
  ushort* wq_bf    = (ushort*)(w8 + 188 * MiB);  // 2 (raw row-major bf16)
  ushort* wk_bf    = (ushort*)(w8 + 190 * MiB);  // 2
  ushort* wv_bf    = (ushort*)(w8 + 192 * MiB);  // 2
  ushort* wo_T     = (ushort*)(w8 + 194 * MiB);  // 2
  ushort* WsT      = (ushort*)(w8 + 196 * MiB);  // 2: wk @ wq^T
  ushort* Wv2T     = (ushort*)(w8 + 198 * MiB);  // 2: wo^T @ wv^T (contig w/ WsT)
  ushort* cwT      = (ushort*)(w8 + 200 * MiB);  // 16 KiB

  prep_k<<<18440, 256, 0, stream>>>(up_w, gate_w, down_w, wq, wk, wv, wo,
                                    conv_w, x, norm_w,
                                    ugw, down_wT, wq_bf, wk_bf, wv_bf, wo_T,
                                    cwT, nrm);

  // ug = normed @ [up_w|gate_w] + biases  (512 blocks = 2 rounds)
  gemm8_k<EP_UG, 256><<<dim3(16, 32), 512, 0, stream>>>(
      nrm, ugw, ug, up_b, gate_b,
      1024, 1024, 1024, 4096, 0, 0, 0, nullptr);

  // 256 weight-product GEMM blocks (128x64 tiles) + 1024 conv blocks
  conv_gate_k<<<1280, 256, 0, stream>>>(ug, cwT, conv_b, combined,
                                        wk_bf, wq_bf, wo_T, wv_bf, WsT, Wv2T);

  // D = combined @ down_w + b  (256 blocks = 1 round)
  gemm8_k<EP_DOWN, 128><<<dim3(4, 64), 512, 0, stream>>>(
      combined, down_wT, nrm, down_b, nullptr,
      2048, 2048, 2048, 1024, 0, 0, 0, nullptr);

  // [G | v'] = D @ [WsT | Wv2T]^T  (256 blocks = 1 round, BM=256)
  gemm8_k<EP_GV, 256><<<dim3(8, 32), 512, 0, stream>>>(
      nrm, WsT, G, nullptr, nullptr,
      1024, 1024, 1024, 1024, 0, 0, 0, vT);

  // S = tril(G @ D^T) * d^(t-s)  (4-wave, 544 active blocks, 2/CU)
  gemm4_k<EP_DECAY><<<dim3(16, 16, Bb), 256, 0, stream>>>(
      G, nrm, S, nullptr, decay,
      1024, 1024, 1024, 2048, LD, LD, (long)Ll * Ll);

  // out = x + S @ v'  (4-wave, 512 blocks, complementary-K pairing)
  gemm4_k<EP_YO><<<dim3(8, 64), 256, 0, stream>>>(
      S, vT, out, x, nullptr,
      0, 2048, 2048, 1024, (long)Ll * Ll, LD, LD);
}